// Round 6
// baseline (227.735 us; speedup 1.0000x reference)
//
#include <hip/hip_runtime.h>
#include <hip/hip_bf16.h>
#include <cstdint>

#define B_ 2
#define C_ 128
#define E_ 60000

typedef unsigned int uint32_;
typedef unsigned short ushort_;
typedef float v2f __attribute__((ext_vector_type(2)));

// unpack two bf16 (dword: low = ch0, high = ch1) to packed float2
__device__ __forceinline__ v2f bp2(uint32_ v) {
    v2f r;
    r.x = __uint_as_float(v << 16);
    r.y = __uint_as_float(v & 0xffff0000u);
    return r;
}

__device__ __forceinline__ v2f vabs2(v2f a) {
    v2f r; r.x = fabsf(a.x); r.y = fabsf(a.y); return r;
}

// float -> bf16 round-to-nearest-even
__device__ __forceinline__ ushort_ f2b(float f) {
    union { float f; uint32_ u; } x; x.f = f;
    uint32_ u = x.u + 0x7fffu + ((x.u >> 16) & 1u);
    return (ushort_)(u >> 16);
}

__device__ __forceinline__ uint32_ packb(float lo, float hi) {
    return (uint32_)f2b(lo) | ((uint32_)f2b(hi) << 16);
}

// within-32-lane-group xor-add via ds_swizzle (and_mask 0x1F keeps halves separate)
__device__ __forceinline__ float swz_add(float v, const int pat) {
    switch (pat) {
    case 1:  return v + __int_as_float(__builtin_amdgcn_ds_swizzle(__float_as_int(v), 0x041F));
    case 2:  return v + __int_as_float(__builtin_amdgcn_ds_swizzle(__float_as_int(v), 0x081F));
    case 4:  return v + __int_as_float(__builtin_amdgcn_ds_swizzle(__float_as_int(v), 0x101F));
    case 8:  return v + __int_as_float(__builtin_amdgcn_ds_swizzle(__float_as_int(v), 0x201F));
    default: return v + __int_as_float(__builtin_amdgcn_ds_swizzle(__float_as_int(v), 0x401F));
    }
}

// ---------------------------------------------------------------------------
// Kernel 0: fold the 256->3 fuse conv into per-path weights (wave-parallel).
// Vw layout: [p][j][s][c] flat (s=0 absorbs the local conv). cst[j] = biases.
// Grid must be 16 blocks (blocks 0..14 = 60 waves of Vw work, block 15 = cst).
// ---------------------------------------------------------------------------
__global__ __launch_bounds__(256) void fuse_weights_kernel(
    const float* __restrict__ Wa_local, const float* __restrict__ ba_local,
    const float* __restrict__ Wb_local, const float* __restrict__ bb_local,
    const float* __restrict__ Wa_tri,  const float* __restrict__ ba_tri,
    const float* __restrict__ Wb_tri,  const float* __restrict__ bb_tri,
    const float* __restrict__ Wa_fuse, const float* __restrict__ ba_fuse,
    const float* __restrict__ Wb_fuse, const float* __restrict__ bb_fuse,
    float* __restrict__ Vw, float* __restrict__ cst)
{
    const int lane = threadIdx.x & 63;
    if (blockIdx.x < 15) {
        const int wid   = blockIdx.x * 4 + (threadIdx.x >> 6); // 0..59
        const int pj    = wid / 10;                            // 0..5
        const int chunk = wid % 10;                            // 0..9
        const int p = pj / 3, j = pj % 3;
        const int f = chunk * 64 + lane;                       // 0..639 = c*5+s
        const float* Wf = p ? Wb_fuse : Wa_fuse;   // [3][256]
        const float* Wt = p ? Wb_tri  : Wa_tri;    // [128][128][5] flat o*640+f
        const float* Wl = p ? Wb_local : Wa_local; // [128][128]
        float a0 = 0.f, a1 = 0.f, a2 = 0.f, a3 = 0.f;
        for (int o = 0; o < C_; o += 4) {
            a0 += Wf[j * 256 + 128 + o]     * Wt[(o)     * 640 + f];
            a1 += Wf[j * 256 + 128 + o + 1] * Wt[(o + 1) * 640 + f];
            a2 += Wf[j * 256 + 128 + o + 2] * Wt[(o + 2) * 640 + f];
            a3 += Wf[j * 256 + 128 + o + 3] * Wt[(o + 3) * 640 + f];
        }
        float acc = (a0 + a1) + (a2 + a3);
        const int s = f % 5, c = f / 5;
        if (s == 0) {   // absorb the local conv into the s=0 slot
            float b0 = 0.f, b1 = 0.f, b2 = 0.f, b3 = 0.f;
            for (int o = 0; o < C_; o += 4) {
                b0 += Wf[j * 256 + o]     * Wl[(o)     * C_ + c];
                b1 += Wf[j * 256 + o + 1] * Wl[(o + 1) * C_ + c];
                b2 += Wf[j * 256 + o + 2] * Wl[(o + 2) * C_ + c];
                b3 += Wf[j * 256 + o + 3] * Wl[(o + 3) * C_ + c];
            }
            acc += (b0 + b1) + (b2 + b3);
        }
        Vw[(pj * 5 + s) * C_ + c] = acc;
    } else {
        if (threadIdx.x < 3) {
            int j = threadIdx.x;
            float acc = ba_fuse[j] + bb_fuse[j];
            for (int o = 0; o < C_; ++o) {
                acc += Wa_fuse[j * 256 + o]       * ba_local[o]
                     + Wa_fuse[j * 256 + 128 + o] * ba_tri[o]
                     + Wb_fuse[j * 256 + o]       * bb_local[o]
                     + Wb_fuse[j * 256 + 128 + o] * bb_tri[o];
            }
            cst[j] = acc;
        }
    }
}

// ---------------------------------------------------------------------------
// Kernel 1: transpose+quantize BOTH inputs into one interleaved buffer.
// y row for (b,e) = 128 dwords: dword 2p = x0 bf16-pair p, 2p+1 = x1 pair p.
// Block = 32e x 64c tile of BOTH x0 and x1 (4 independent dwordx4 loads per
// thread for MLP). Write: 2 uint4 per thread, full 512 B rows coalesced.
// ---------------------------------------------------------------------------
__global__ __launch_bounds__(256) void transpose_interleave_kernel(
    const float* __restrict__ x0, const float* __restrict__ x1,
    uint32_* __restrict__ y)
{
    __shared__ float tA[32][65];
    __shared__ float tB[32][65];
    const int b  = blockIdx.z;
    const int e0 = blockIdx.x * 32;
    const int c0 = blockIdx.y * 64;
    const float* s0 = x0 + (size_t)b * C_ * E_;
    const float* s1 = x1 + (size_t)b * C_ * E_;
    const int t = threadIdx.x;
    {
        const int c  = t >> 2;          // 0..63
        const int e8 = (t & 3) * 8;     // 0,8,16,24
        const float* p0 = s0 + (size_t)(c0 + c) * E_ + e0 + e8;
        const float* p1 = s1 + (size_t)(c0 + c) * E_ + e0 + e8;
        float4 u0 = *(const float4*)p0;
        float4 u1 = *(const float4*)(p0 + 4);
        float4 v0 = *(const float4*)p1;
        float4 v1 = *(const float4*)(p1 + 4);
        tA[e8 + 0][c] = u0.x; tA[e8 + 1][c] = u0.y;
        tA[e8 + 2][c] = u0.z; tA[e8 + 3][c] = u0.w;
        tA[e8 + 4][c] = u1.x; tA[e8 + 5][c] = u1.y;
        tA[e8 + 6][c] = u1.z; tA[e8 + 7][c] = u1.w;
        tB[e8 + 0][c] = v0.x; tB[e8 + 1][c] = v0.y;
        tB[e8 + 2][c] = v0.z; tB[e8 + 3][c] = v0.w;
        tB[e8 + 4][c] = v1.x; tB[e8 + 5][c] = v1.y;
        tB[e8 + 6][c] = v1.z; tB[e8 + 7][c] = v1.w;
    }
    __syncthreads();
    {
        const int e  = t >> 3;          // 0..31
        const int c8 = (t & 7) * 8;     // channel offset within 64-c tile
        const float* ra = &tA[e][c8];
        const float* rb = &tB[e][c8];
        uint4 w0, w1;
        w0.x = packb(ra[0], ra[1]); w0.y = packb(rb[0], rb[1]);
        w0.z = packb(ra[2], ra[3]); w0.w = packb(rb[2], rb[3]);
        w1.x = packb(ra[4], ra[5]); w1.y = packb(rb[4], rb[5]);
        w1.z = packb(ra[6], ra[7]); w1.w = packb(rb[6], rb[7]);
        uint32_* drow = y + (((size_t)(b * E_ + e0 + e)) << 7) + c0 + c8;
        *(uint4*)(drow)     = w0;
        *(uint4*)(drow + 4) = w1;
    }
}

// ---------------------------------------------------------------------------
// Kernel 2: fused gather + features + 3-channel projection.
// Two edges per wave-iteration; each gather is one dwordx2 (x0 pair + x1 pair
// for this lane's channels) from the interleaved y buffer -> 10 gathers/iter.
// ---------------------------------------------------------------------------
__global__ __launch_bounds__(256, 4) void mesh_fused_kernel(
    const uint2* __restrict__ y, const int* __restrict__ gemm,
    const float* __restrict__ Vw, const float* __restrict__ cst,
    float* __restrict__ out)
{
    const int lane = threadIdx.x & 63;
    const int wv   = threadIdx.x >> 6;
    const int gw   = blockIdx.x * 4 + wv;
    const int nw   = gridDim.x * 4;

    v2f w[2][3][5];
#pragma unroll
    for (int p = 0; p < 2; ++p)
#pragma unroll
        for (int j = 0; j < 3; ++j)
#pragma unroll
            for (int s = 0; s < 5; ++s)
                w[p][j][s] = *(const v2f*)(Vw + (((p * 3 + j) * 5 + s) << 7) + lane * 2);

    const int  jj     = lane >> 4;                 // 0..3
    const bool is0    = (jj == 0), is1 = (jj == 1);
    const bool writer = ((lane & 15) == 0) && (jj < 3);
    const float cj    = is0 ? cst[0] : (is1 ? cst[1] : cst[2]);
    float* obase      = out + (size_t)(jj < 3 ? jj : 2) * E_;

    const int4* g4 = (const int4*)gemm;
    const int npair = (B_ * E_) / 2;

    int4 giA = make_int4(0, 0, 0, 0), giB = giA;
    if (gw < npair) { giA = g4[2 * gw]; giB = g4[2 * gw + 1]; }

    for (int pair = gw; pair < npair; pair += nw) {
        const int nxt = pair + nw;
        const int4 gA = giA, gB = giB;
        if (nxt < npair) { giA = g4[2 * nxt]; giB = g4[2 * nxt + 1]; }  // prefetch

        const int e0 = 2 * pair;
        const int b  = (e0 >= E_) ? 1 : 0;
        const int e  = e0 - (b ? E_ : 0);
        const uint2* Y = y + (size_t)b * (E_ * 64);   // row = 64 uint2

        const uint32_ sA  = ((uint32_)e    << 6) + lane;
        const uint32_ sB  = sA + 64;
        const uint32_ oA1 = ((uint32_)gA.x << 6) + lane;
        const uint32_ oA2 = ((uint32_)gA.y << 6) + lane;
        const uint32_ oA3 = ((uint32_)gA.z << 6) + lane;
        const uint32_ oA4 = ((uint32_)gA.w << 6) + lane;
        const uint32_ oB1 = ((uint32_)gB.x << 6) + lane;
        const uint32_ oB2 = ((uint32_)gB.y << 6) + lane;
        const uint32_ oB3 = ((uint32_)gB.z << 6) + lane;
        const uint32_ oB4 = ((uint32_)gB.w << 6) + lane;

        // 10 independent dwordx2 gathers (each = x0 pair + x1 pair)
        const uint2 PA0 = Y[sA],  PA1 = Y[oA1], PA2 = Y[oA2],
                    PA3 = Y[oA3], PA4 = Y[oA4];
        const uint2 PB0 = Y[sB],  PB1 = Y[oB1], PB2 = Y[oB2],
                    PB3 = Y[oB3], PB4 = Y[oB4];

        // ---- edge A ----
        float rA0, rA1, rA2;
        {
            v2f a0 = bp2(PA0.x), a1 = bp2(PA1.x), a2 = bp2(PA2.x),
                a3 = bp2(PA3.x), a4 = bp2(PA4.x);
            v2f b0 = bp2(PA0.y), b1 = bp2(PA1.y), b2 = bp2(PA2.y),
                b3 = bp2(PA3.y), b4 = bp2(PA4.y);
            v2f sa1 = a1 + a3, sa2 = a2 + a4;
            v2f da1 = vabs2(a1 - a3), da2 = vabs2(a2 - a4);
            v2f sb1 = b1 + b3, sb2 = b2 + b4;
            v2f db1 = vabs2(b1 - b3), db2 = vabs2(b2 - b4);
            v2f t0 = w[0][0][0] * a0, t1 = w[0][1][0] * a0, t2 = w[0][2][0] * a0;
            t0 += w[0][0][1] * sa1; t1 += w[0][1][1] * sa1; t2 += w[0][2][1] * sa1;
            t0 += w[0][0][2] * sa2; t1 += w[0][1][2] * sa2; t2 += w[0][2][2] * sa2;
            t0 += w[0][0][3] * da1; t1 += w[0][1][3] * da1; t2 += w[0][2][3] * da1;
            t0 += w[0][0][4] * da2; t1 += w[0][1][4] * da2; t2 += w[0][2][4] * da2;
            t0 += w[1][0][0] * b0;  t1 += w[1][1][0] * b0;  t2 += w[1][2][0] * b0;
            t0 += w[1][0][1] * sb1; t1 += w[1][1][1] * sb1; t2 += w[1][2][1] * sb1;
            t0 += w[1][0][2] * sb2; t1 += w[1][1][2] * sb2; t2 += w[1][2][2] * sb2;
            t0 += w[1][0][3] * db1; t1 += w[1][1][3] * db1; t2 += w[1][2][3] * db1;
            t0 += w[1][0][4] * db2; t1 += w[1][1][4] * db2; t2 += w[1][2][4] * db2;
            rA0 = t0.x + t0.y; rA1 = t1.x + t1.y; rA2 = t2.x + t2.y;
        }
        // ---- edge B ----
        float rB0, rB1, rB2;
        {
            v2f a0 = bp2(PB0.x), a1 = bp2(PB1.x), a2 = bp2(PB2.x),
                a3 = bp2(PB3.x), a4 = bp2(PB4.x);
            v2f b0 = bp2(PB0.y), b1 = bp2(PB1.y), b2 = bp2(PB2.y),
                b3 = bp2(PB3.y), b4 = bp2(PB4.y);
            v2f sa1 = a1 + a3, sa2 = a2 + a4;
            v2f da1 = vabs2(a1 - a3), da2 = vabs2(a2 - a4);
            v2f sb1 = b1 + b3, sb2 = b2 + b4;
            v2f db1 = vabs2(b1 - b3), db2 = vabs2(b2 - b4);
            v2f t0 = w[0][0][0] * a0, t1 = w[0][1][0] * a0, t2 = w[0][2][0] * a0;
            t0 += w[0][0][1] * sa1; t1 += w[0][1][1] * sa1; t2 += w[0][2][1] * sa1;
            t0 += w[0][0][2] * sa2; t1 += w[0][1][2] * sa2; t2 += w[0][2][2] * sa2;
            t0 += w[0][0][3] * da1; t1 += w[0][1][3] * da1; t2 += w[0][2][3] * da1;
            t0 += w[0][0][4] * da2; t1 += w[0][1][4] * da2; t2 += w[0][2][4] * da2;
            t0 += w[1][0][0] * b0;  t1 += w[1][1][0] * b0;  t2 += w[1][2][0] * b0;
            t0 += w[1][0][1] * sb1; t1 += w[1][1][1] * sb1; t2 += w[1][2][1] * sb1;
            t0 += w[1][0][2] * sb2; t1 += w[1][1][2] * sb2; t2 += w[1][2][2] * sb2;
            t0 += w[1][0][3] * db1; t1 += w[1][1][3] * db1; t2 += w[1][2][3] * db1;
            t0 += w[1][0][4] * db2; t1 += w[1][1][4] * db2; t2 += w[1][2][4] * db2;
            rB0 = t0.x + t0.y; rB1 = t1.x + t1.y; rB2 = t2.x + t2.y;
        }

        // partial reduce (independent A/B chains interleaved for pipe overlap)
        rA0 = swz_add(rA0, 16); rB0 = swz_add(rB0, 16);
        rA1 = swz_add(rA1, 16); rB1 = swz_add(rB1, 16);
        rA2 = swz_add(rA2, 16); rB2 = swz_add(rB2, 16);
        rA0 += __shfl_xor(rA0, 32, 64); rB0 += __shfl_xor(rB0, 32, 64);
        rA1 += __shfl_xor(rA1, 32, 64); rB1 += __shfl_xor(rB1, 32, 64);
        rA2 += __shfl_xor(rA2, 32, 64); rB2 += __shfl_xor(rB2, 32, 64);

        float vA = is0 ? rA0 : (is1 ? rA1 : rA2);
        float vB = is0 ? rB0 : (is1 ? rB1 : rB2);
        vA = swz_add(vA, 1); vB = swz_add(vB, 1);
        vA = swz_add(vA, 2); vB = swz_add(vB, 2);
        vA = swz_add(vA, 4); vB = swz_add(vB, 4);
        vA = swz_add(vA, 8); vB = swz_add(vB, 8);

        if (writer) {
            float2 st; st.x = vA + cj; st.y = vB + cj;
            *(float2*)(obase + (b ? 3 * E_ : 0) + e) = st;   // e even -> aligned
        }
    }
}

extern "C" void kernel_launch(void* const* d_in, const int* in_sizes, int n_in,
                              void* d_out, int out_size, void* d_ws, size_t ws_size,
                              hipStream_t stream) {
    const float* x0       = (const float*)d_in[0];
    const float* x1       = (const float*)d_in[1];
    const int*   gemm     = (const int*)d_in[2];
    const float* Wa_local = (const float*)d_in[3];
    const float* ba_local = (const float*)d_in[4];
    const float* Wb_local = (const float*)d_in[5];
    const float* bb_local = (const float*)d_in[6];
    const float* Wa_tri   = (const float*)d_in[7];
    const float* ba_tri   = (const float*)d_in[8];
    const float* Wb_tri   = (const float*)d_in[9];
    const float* bb_tri   = (const float*)d_in[10];
    const float* Wa_fuse  = (const float*)d_in[11];
    const float* ba_fuse  = (const float*)d_in[12];
    const float* Wb_fuse  = (const float*)d_in[13];
    const float* bb_fuse  = (const float*)d_in[14];
    float* out = (float*)d_out;

    uint32_* y   = (uint32_*)d_ws;                        // B*E*128 dwords
    float*   Vw  = (float*)(y + (size_t)B_ * E_ * 128);
    float*   cst = Vw + 2 * 3 * 5 * C_;

    hipLaunchKernelGGL(fuse_weights_kernel, dim3(16), dim3(256), 0, stream,
                       Wa_local, ba_local, Wb_local, bb_local,
                       Wa_tri, ba_tri, Wb_tri, bb_tri,
                       Wa_fuse, ba_fuse, Wb_fuse, bb_fuse, Vw, cst);

    hipLaunchKernelGGL(transpose_interleave_kernel, dim3(E_ / 32, C_ / 64, B_),
                       dim3(256), 0, stream, x0, x1, y);

    hipLaunchKernelGGL(mesh_fused_kernel, dim3(2048), dim3(256), 0, stream,
                       (const uint2*)y, gemm, Vw, cst, out);
}